// Round 1
// baseline (87733.173 us; speedup 1.0000x reference)
//
#include <hip/hip_runtime.h>
#include <math.h>

#define NN 4096
#define KK 8
#define DD 512
#define HH 512
#define NB 256
#define TPB 256
#define TOT (NB * TPB)
#define MAXR 8192

// ws layout (bytes)
#define OFF_CTRL 0                         // [0]=bar_cnt [1]=bar_gen
#define OFF_STATE (256)                    // int state[NN]
#define OFF_CNT (OFF_STATE + 4 * NN)       // int cntArr[MAXR]
#define OFF_RLEN (OFF_CNT + 4 * MAXR)      // int rlenArr[MAXR]
#define OFF_LIST0 (OFF_RLEN + 4 * MAXR)    // int list0[NN]
#define OFF_LIST1 (OFF_LIST0 + 4 * NN)     // int list1[NN]
#define OFF_H (OFF_LIST1 + 4 * NN)         // float hbuf[2][2][NN][HH]
#define OFF_C (OFF_H + 4 * 2 * 2 * NN * HH) // float cbuf[2][NN][HH]
#define WS_ZERO_BYTES OFF_LIST0

__device__ __forceinline__ float sigm(float x) { return 1.0f / (1.0f + __expf(-x)); }

__device__ __forceinline__ void grid_barrier(int* bar) {
    __syncthreads();
    if (threadIdx.x == 0) {
        __threadfence();
        int g = __hip_atomic_load(bar + 1, __ATOMIC_RELAXED, __HIP_MEMORY_SCOPE_AGENT);
        int a = __hip_atomic_fetch_add(bar + 0, 1, __ATOMIC_ACQ_REL, __HIP_MEMORY_SCOPE_AGENT);
        if (a == NB - 1) {
            __hip_atomic_store(bar + 0, 0, __ATOMIC_RELAXED, __HIP_MEMORY_SCOPE_AGENT);
            __hip_atomic_store(bar + 1, g + 1, __ATOMIC_RELEASE, __HIP_MEMORY_SCOPE_AGENT);
        } else {
            while (__hip_atomic_load(bar + 1, __ATOMIC_ACQUIRE, __HIP_MEMORY_SCOPE_AGENT) == g) {
                __builtin_amdgcn_s_sleep(1);
            }
        }
        __threadfence();
    }
    __syncthreads();
}

__global__ void __launch_bounds__(TPB, 2)
tree_lstm_kernel(const float* __restrict__ x0,
                 const float* __restrict__ Wl_ih, const float* __restrict__ Wl_hh,
                 const float* __restrict__ bl_ih, const float* __restrict__ bl_hh,
                 const float* __restrict__ Wr_ih, const float* __restrict__ Wr_hh,
                 const float* __restrict__ br_ih, const float* __restrict__ br_hh,
                 const float* __restrict__ W_enc, const float* __restrict__ b_enc,
                 const int* __restrict__ lch, const int* __restrict__ rch,
                 float* ctx, char* ws) {
    const int tid  = threadIdx.x;
    const int gtid = blockIdx.x * TPB + tid;
    const int wave = gtid >> 6;   // 0..1023 == (side, unit)
    const int lane = tid & 63;
    const int side = wave >> 9;   // 0 = left chain, 1 = right chain
    const int u    = wave & 511;  // hidden unit owned by this wave

    int*   bar     = (int*)(ws + OFF_CTRL);
    int*   state   = (int*)(ws + OFF_STATE);
    int*   cntArr  = (int*)(ws + OFF_CNT);
    int*   rlenArr = (int*)(ws + OFF_RLEN);
    int*   list0   = (int*)(ws + OFF_LIST0);
    int*   list1   = (int*)(ws + OFF_LIST1);
    float* hbuf    = (float*)(ws + OFF_H);  // [parity][side][node][unit]
    float* cbuf    = (float*)(ws + OFF_C);  // [side][node][unit]

    const float* Wih = side ? Wr_ih : Wl_ih;
    const float* Whh = side ? Wr_hh : Wl_hh;
    const float* bih = side ? br_ih : bl_ih;
    const float* bhh = side ? br_hh : bl_hh;
    const int*   CH  = side ? rch : lch;

    // Hoist this wave's gate rows into registers for the whole kernel.
    // Lane l covers columns [8l, 8l+8). Gate order i,f,g,o (rows g*512+u).
    float wih[4][8], whh[4][8], bsum[4];
#pragma unroll
    for (int g = 0; g < 4; ++g) {
        const size_t row = (size_t)g * HH + u;
        const float4 wa = *(const float4*)(Wih + row * DD + lane * 8);
        const float4 wb = *(const float4*)(Wih + row * DD + lane * 8 + 4);
        wih[g][0] = wa.x; wih[g][1] = wa.y; wih[g][2] = wa.z; wih[g][3] = wa.w;
        wih[g][4] = wb.x; wih[g][5] = wb.y; wih[g][6] = wb.z; wih[g][7] = wb.w;
        const float4 ha = *(const float4*)(Whh + row * HH + lane * 8);
        const float4 hb = *(const float4*)(Whh + row * HH + lane * 8 + 4);
        whh[g][0] = ha.x; whh[g][1] = ha.y; whh[g][2] = ha.z; whh[g][3] = ha.w;
        whh[g][4] = hb.x; whh[g][5] = hb.y; whh[g][6] = hb.z; whh[g][7] = hb.w;
        bsum[g] = bih[row] + bhh[row];
    }
    // Enc: wave owns output dim d=u; lane covers 16 cols (lanes 0-31 -> hl, 32-63 -> hr).
    float wenc[16];
#pragma unroll
    for (int j = 0; j < 4; ++j) {
        const float4 t = *(const float4*)(W_enc + (size_t)u * (2 * HH) + lane * 16 + j * 4);
        wenc[j * 4 + 0] = t.x; wenc[j * 4 + 1] = t.y; wenc[j * 4 + 2] = t.z; wenc[j * 4 + 3] = t.w;
    }
    const float bencv = b_enc[u];

    int r = 0, doneSum = 0, Bprev = 0;
    while (doneSum < NN && r < MAXR - 2) {
        int* curList  = (r & 1) ? list1 : list0;
        int* prevList = (r & 1) ? list0 : list1;

        // phase S: mark previous round's nodes done
        for (int s = gtid; s < Bprev; s += TOT) state[prevList[s]] = 2;
        // phase A: activate nodes whose children are all done
        if (gtid < NN) {
            const int i = gtid;
            if (state[i] == 0) {
                bool ok = true;
                int  len = 1;
#pragma unroll
                for (int k = 0; k < KK; ++k) {
                    const int c = lch[i * KK + k];
                    if (c >= 0) { if (k + 2 > len) len = k + 2; if (state[c] != 2) ok = false; }
                }
#pragma unroll
                for (int k = 0; k < KK; ++k) {
                    const int c = rch[i * KK + k];
                    if (c >= 0) { if (k + 2 > len) len = k + 2; if (state[c] != 2) ok = false; }
                }
                if (ok) {
                    state[i] = 1;
                    const int pos = atomicAdd(&cntArr[r], 1);
                    curList[pos] = i;
                    atomicMax(&rlenArr[r], len);
                }
            }
        }
        grid_barrier(bar);
        const int B = __hip_atomic_load(&cntArr[r], __ATOMIC_RELAXED, __HIP_MEMORY_SCOPE_AGENT);
        const int L = __hip_atomic_load(&rlenArr[r], __ATOMIC_RELAXED, __HIP_MEMORY_SCOPE_AGENT);
        doneSum += B;

        // lockstep chain sub-steps; h double-buffered by step parity
        for (int q = 0; q < L; ++q) {
            const size_t parW = (size_t)(q & 1);
            float*       hb_w = hbuf + (parW * 2 + side) * (size_t)(NN * HH);
            const float* hb_r = hbuf + ((parW ^ 1) * 2 + side) * (size_t)(NN * HH);
            float*       cb   = cbuf + (size_t)side * (NN * HH);
            for (int slot = 0; slot < B; ++slot) {
                const int i = curList[slot];
                const float* xv;
                if (q == 0) {
                    xv = x0 + (size_t)i * DD;
                } else {
                    const int c = CH[i * KK + (q - 1)];
                    if (c < 0) {  // masked step: carry h forward to keep parity uniform
                        if (lane == 0) hb_w[(size_t)i * HH + u] = hb_r[(size_t)i * HH + u];
                        continue;
                    }
                    xv = ctx + (size_t)c * DD;
                }
                const float4 xa = *(const float4*)(xv + lane * 8);
                const float4 xb = *(const float4*)(xv + lane * 8 + 4);
                float xr[8] = {xa.x, xa.y, xa.z, xa.w, xb.x, xb.y, xb.z, xb.w};
                float acc[4];
#pragma unroll
                for (int g = 0; g < 4; ++g) {
                    float s = 0.f;
#pragma unroll
                    for (int j = 0; j < 8; ++j) s += wih[g][j] * xr[j];
                    acc[g] = s;
                }
                if (q > 0) {
                    const float* hv = hb_r + (size_t)i * HH + lane * 8;
                    const float4 hA = *(const float4*)(hv);
                    const float4 hB = *(const float4*)(hv + 4);
                    float hr8[8] = {hA.x, hA.y, hA.z, hA.w, hB.x, hB.y, hB.z, hB.w};
#pragma unroll
                    for (int g = 0; g < 4; ++g) {
                        float s = acc[g];
#pragma unroll
                        for (int j = 0; j < 8; ++j) s += whh[g][j] * hr8[j];
                        acc[g] = s;
                    }
                }
#pragma unroll
                for (int m = 1; m < 64; m <<= 1) {
                    acc[0] += __shfl_xor(acc[0], m, 64);
                    acc[1] += __shfl_xor(acc[1], m, 64);
                    acc[2] += __shfl_xor(acc[2], m, 64);
                    acc[3] += __shfl_xor(acc[3], m, 64);
                }
                if (lane == 0) {
                    const float gi = acc[0] + bsum[0];
                    const float gf = acc[1] + bsum[1];
                    const float gg = acc[2] + bsum[2];
                    const float go = acc[3] + bsum[3];
                    const float cp = (q == 0) ? 0.0f : cb[(size_t)i * HH + u];
                    const float cn = sigm(gf) * cp + sigm(gi) * tanhf(gg);
                    cb[(size_t)i * HH + u]   = cn;
                    hb_w[(size_t)i * HH + u] = sigm(go) * tanhf(cn);
                }
            }
            grid_barrier(bar);
        }

        // enc: ctx[i][d] = tanh(W_enc[d] . [hl|hr] + b_enc[d])
        if (B > 0) {
            const float* hfin  = hbuf + (size_t)(((L - 1) & 1) * 2) * (NN * HH);
            const float* hbase = hfin + (size_t)(lane >> 5) * (NN * HH);
            const int    col   = (lane * 16) & 511;
            for (int slot = (wave >> 9); slot < B; slot += 2) {
                const int    i  = curList[slot];
                const float* hv = hbase + (size_t)i * HH + col;
                float acc = 0.f;
#pragma unroll
                for (int j = 0; j < 4; ++j) {
                    const float4 t = *(const float4*)(hv + j * 4);
                    acc += wenc[j * 4 + 0] * t.x + wenc[j * 4 + 1] * t.y +
                           wenc[j * 4 + 2] * t.z + wenc[j * 4 + 3] * t.w;
                }
#pragma unroll
                for (int m = 1; m < 64; m <<= 1) acc += __shfl_xor(acc, m, 64);
                if (lane == 0) ctx[(size_t)i * DD + u] = tanhf(acc + bencv);
            }
        }
        grid_barrier(bar);
        Bprev = B;
        ++r;
    }
}

extern "C" void kernel_launch(void* const* d_in, const int* in_sizes, int n_in,
                              void* d_out, int out_size, void* d_ws, size_t ws_size,
                              hipStream_t stream) {
    hipMemsetAsync(d_ws, 0, WS_ZERO_BYTES, stream);
    tree_lstm_kernel<<<dim3(NB), dim3(TPB), 0, stream>>>(
        (const float*)d_in[0],
        (const float*)d_in[1], (const float*)d_in[2],
        (const float*)d_in[3], (const float*)d_in[4],
        (const float*)d_in[5], (const float*)d_in[6],
        (const float*)d_in[7], (const float*)d_in[8],
        (const float*)d_in[9], (const float*)d_in[10],
        (const int*)d_in[11], (const int*)d_in[12],
        (float*)d_out, (char*)d_ws);
}

// Round 2
// 70280.396 us; speedup vs baseline: 1.2483x; 1.2483x over previous
//
#include <hip/hip_runtime.h>
#include <math.h>

#define NN 4096
#define KK 8
#define DD 512
#define HH 512
#define NB 256
#define TPB 512
#define TOT (NB * TPB)
#define MAXR 8192
#define NNHH ((size_t)NN * HH)

// ws layout (bytes)
#define OFF_CTRL 0                         // [0]=bar_cnt [1]=bar_gen
#define OFF_STATE (256)                    // int state[NN]
#define OFF_CNT (OFF_STATE + 4 * NN)       // int cntArr[MAXR]
#define OFF_RLEN (OFF_CNT + 4 * MAXR)      // int rlenArr[MAXR]
#define OFF_LIST0 (OFF_RLEN + 4 * MAXR)    // int list0[NN] (packed i|lenL<<12|lenR<<16)
#define OFF_LIST1 (OFF_LIST0 + 4 * NN)     // int list1[NN]
#define OFF_H (OFF_LIST1 + 4 * NN)         // float hbuf[2][2][NN][HH]  (parity, side)
#define OFF_C (OFF_H + 4 * 2 * 2 * NN * HH) // float cbuf[2][NN][HH]
#define WS_ZERO_BYTES OFF_LIST0

__device__ __forceinline__ float sigm(float x) { return 1.0f / (1.0f + __expf(-x)); }

__device__ __forceinline__ void grid_barrier(int* bar) {
    __syncthreads();
    if (threadIdx.x == 0) {
        __threadfence();
        int g = __hip_atomic_load(bar + 1, __ATOMIC_RELAXED, __HIP_MEMORY_SCOPE_AGENT);
        int a = __hip_atomic_fetch_add(bar + 0, 1, __ATOMIC_ACQ_REL, __HIP_MEMORY_SCOPE_AGENT);
        if (a == NB - 1) {
            __hip_atomic_store(bar + 0, 0, __ATOMIC_RELAXED, __HIP_MEMORY_SCOPE_AGENT);
            __hip_atomic_store(bar + 1, g + 1, __ATOMIC_RELEASE, __HIP_MEMORY_SCOPE_AGENT);
        } else {
            while (__hip_atomic_load(bar + 1, __ATOMIC_ACQUIRE, __HIP_MEMORY_SCOPE_AGENT) == g) {
                __builtin_amdgcn_s_sleep(1);
            }
        }
        __threadfence();
    }
    __syncthreads();
}

__global__ void __launch_bounds__(TPB, 2)
tree_lstm_kernel(const float* __restrict__ x0,
                 const float* __restrict__ Wl_ih, const float* __restrict__ Wl_hh,
                 const float* __restrict__ bl_ih, const float* __restrict__ bl_hh,
                 const float* __restrict__ Wr_ih, const float* __restrict__ Wr_hh,
                 const float* __restrict__ br_ih, const float* __restrict__ br_hh,
                 const float* __restrict__ W_enc, const float* __restrict__ b_enc,
                 const int* __restrict__ lch, const int* __restrict__ rch,
                 float* ctx, char* ws) {
    const int tid  = threadIdx.x;
    const int gtid = blockIdx.x * TPB + tid;
    const int wave = gtid >> 6;        // 0..2047
    const int lane = tid & 63;
    const int u    = wave & 511;       // hidden unit owned by this wave
    const int side = (wave >> 9) & 1;  // 0 = left chain, 1 = right chain
    const int p    = wave >> 10;       // slot-split: this wave handles slots s with s%2==p
    const int egrp = (wave >> 9) & 3;  // enc: 4-way slot split

    int*   bar     = (int*)(ws + OFF_CTRL);
    int*   state   = (int*)(ws + OFF_STATE);
    int*   cntArr  = (int*)(ws + OFF_CNT);
    int*   rlenArr = (int*)(ws + OFF_RLEN);
    int*   list0   = (int*)(ws + OFF_LIST0);
    int*   list1   = (int*)(ws + OFF_LIST1);
    float* hbuf    = (float*)(ws + OFF_H);
    float* cbuf    = (float*)(ws + OFF_C);

    const float* Wih = side ? Wr_ih : Wl_ih;
    const float* Whh = side ? Wr_hh : Wl_hh;
    const float* bih = side ? br_ih : bl_ih;
    const float* bhh = side ? br_hh : bl_hh;
    const int*   CH  = side ? rch : lch;

    // Hoist this wave's 4 gate rows (ih + hh) into registers for the kernel's
    // lifetime. Lane l covers columns [8l, 8l+8). Gate order i,f,g,o.
    float wih[4][8], whh[4][8], bsum[4];
#pragma unroll
    for (int g = 0; g < 4; ++g) {
        const size_t row = (size_t)g * HH + u;
        const float4 wa = *(const float4*)(Wih + row * DD + lane * 8);
        const float4 wb = *(const float4*)(Wih + row * DD + lane * 8 + 4);
        wih[g][0] = wa.x; wih[g][1] = wa.y; wih[g][2] = wa.z; wih[g][3] = wa.w;
        wih[g][4] = wb.x; wih[g][5] = wb.y; wih[g][6] = wb.z; wih[g][7] = wb.w;
        const float4 ha = *(const float4*)(Whh + row * HH + lane * 8);
        const float4 hb = *(const float4*)(Whh + row * HH + lane * 8 + 4);
        whh[g][0] = ha.x; whh[g][1] = ha.y; whh[g][2] = ha.z; whh[g][3] = ha.w;
        whh[g][4] = hb.x; whh[g][5] = hb.y; whh[g][6] = hb.z; whh[g][7] = hb.w;
        bsum[g] = bih[row] + bhh[row];
    }
    // Enc row u: lane covers 16 cols (lanes 0-31 -> hl, 32-63 -> hr).
    float wenc[16];
#pragma unroll
    for (int j = 0; j < 4; ++j) {
        const float4 t = *(const float4*)(W_enc + (size_t)u * (2 * HH) + lane * 16 + j * 4);
        wenc[j * 4 + 0] = t.x; wenc[j * 4 + 1] = t.y; wenc[j * 4 + 2] = t.z; wenc[j * 4 + 3] = t.w;
    }
    const float bencv = b_enc[u];

    int r = 0, doneSum = 0, Bprev = 0;
    while (doneSum < NN && r < MAXR - 2) {
        int* curList  = (r & 1) ? list1 : list0;
        int* prevList = (r & 1) ? list0 : list1;

        // phase S: mark previous round's nodes done
        for (int s = gtid; s < Bprev; s += TOT) state[prevList[s] & 0xFFF] = 2;
        // phase A: activate nodes whose children are all done; pack lens
        if (gtid < NN) {
            const int i = gtid;
            if (state[i] == 0) {
                bool ok = true;
                int ll = 1, lr = 1;
#pragma unroll
                for (int k = 0; k < KK; ++k) {
                    const int c = lch[i * KK + k];
                    if (c >= 0) { ll = k + 2; if (state[c] != 2) ok = false; }
                }
#pragma unroll
                for (int k = 0; k < KK; ++k) {
                    const int c = rch[i * KK + k];
                    if (c >= 0) { lr = k + 2; if (state[c] != 2) ok = false; }
                }
                if (ok) {
                    state[i] = 1;
                    const int pos = atomicAdd(&cntArr[r], 1);
                    curList[pos] = i | (ll << 12) | (lr << 16);
                    atomicMax(&rlenArr[r], ll > lr ? ll : lr);
                }
            }
        }
        grid_barrier(bar);
        const int B = __hip_atomic_load(&cntArr[r], __ATOMIC_RELAXED, __HIP_MEMORY_SCOPE_AGENT);
        const int L = __hip_atomic_load(&rlenArr[r], __ATOMIC_RELAXED, __HIP_MEMORY_SCOPE_AGENT);
        doneSum += B;

        // lockstep chain sub-steps; h double-buffered by step parity.
        // Nodes whose chain (this side) ended are skipped; enc reads their
        // final h at parity (len-1)&1.
        const int shift = 12 + 4 * side;
        for (int q = 0; q < L; ++q) {
            float*       hb_w = hbuf + (size_t)((q & 1) * 2 + side) * NNHH;
            const float* hb_r = hbuf + (size_t)((((q & 1) ^ 1)) * 2 + side) * NNHH;
            float*       cb   = cbuf + (size_t)side * NNHH;
            for (int s0 = p; s0 < B; s0 += 8) {
                int   im[4];
                bool  act[4];
                float xr[4][8], hr[4][8], cp[4];
                // gather phase: resolve slots, issue all loads
#pragma unroll
                for (int k = 0; k < 4; ++k) {
                    const int s = s0 + 2 * k;
                    act[k] = false; im[k] = 0; cp[k] = 0.f;
                    if (s < B) {
                        const int e   = curList[s];
                        const int i   = e & 0xFFF;
                        const int len = (e >> shift) & 0xF;
                        if (q < len) { act[k] = true; im[k] = i; }
                    }
                }
#pragma unroll
                for (int k = 0; k < 4; ++k) {
                    if (!act[k]) continue;
                    const int i = im[k];
                    const float* xv = (q == 0) ? (x0 + (size_t)i * DD)
                                               : (ctx + (size_t)CH[i * KK + (q - 1)] * DD);
                    const float4 xa = *(const float4*)(xv + lane * 8);
                    const float4 xb = *(const float4*)(xv + lane * 8 + 4);
                    xr[k][0] = xa.x; xr[k][1] = xa.y; xr[k][2] = xa.z; xr[k][3] = xa.w;
                    xr[k][4] = xb.x; xr[k][5] = xb.y; xr[k][6] = xb.z; xr[k][7] = xb.w;
                    if (q > 0) {
                        const float* hv = hb_r + (size_t)i * HH + lane * 8;
                        const float4 hA = *(const float4*)(hv);
                        const float4 hB = *(const float4*)(hv + 4);
                        hr[k][0] = hA.x; hr[k][1] = hA.y; hr[k][2] = hA.z; hr[k][3] = hA.w;
                        hr[k][4] = hB.x; hr[k][5] = hB.y; hr[k][6] = hB.z; hr[k][7] = hB.w;
                        cp[k] = cb[(size_t)i * HH + u];  // broadcast load
                    }
                }
                // compute phase: 4 independent slots' FMA + reduce chains
#pragma unroll
                for (int k = 0; k < 4; ++k) {
                    if (!act[k]) continue;
                    const int i = im[k];
                    float a0 = 0.f, a1 = 0.f, a2 = 0.f, a3 = 0.f;
#pragma unroll
                    for (int j = 0; j < 8; ++j) {
                        a0 += wih[0][j] * xr[k][j];
                        a1 += wih[1][j] * xr[k][j];
                        a2 += wih[2][j] * xr[k][j];
                        a3 += wih[3][j] * xr[k][j];
                    }
                    if (q > 0) {
#pragma unroll
                        for (int j = 0; j < 8; ++j) {
                            a0 += whh[0][j] * hr[k][j];
                            a1 += whh[1][j] * hr[k][j];
                            a2 += whh[2][j] * hr[k][j];
                            a3 += whh[3][j] * hr[k][j];
                        }
                    }
                    // multi-gate butterfly: after this, lane l holds gate (l&3)
                    float v01, v23, v;
                    {
                        const bool hi = lane & 1;
                        float keep = hi ? a1 : a0, send = hi ? a0 : a1;
                        v01 = keep + __shfl_xor(send, 1, 64);
                        keep = hi ? a3 : a2; send = hi ? a2 : a3;
                        v23 = keep + __shfl_xor(send, 1, 64);
                    }
                    {
                        const bool hi = lane & 2;
                        const float keep = hi ? v23 : v01, send = hi ? v01 : v23;
                        v = keep + __shfl_xor(send, 2, 64);
                    }
                    v += __shfl_xor(v, 4, 64);
                    v += __shfl_xor(v, 8, 64);
                    v += __shfl_xor(v, 16, 64);
                    v += __shfl_xor(v, 32, 64);
                    const float g1 = __shfl(v, 1, 64);
                    const float g2 = __shfl(v, 2, 64);
                    const float g3 = __shfl(v, 3, 64);
                    // valid on lane 0 only (v there = gate i)
                    const float gi = v  + bsum[0];
                    const float gf = g1 + bsum[1];
                    const float gg = g2 + bsum[2];
                    const float go = g3 + bsum[3];
                    const float cn = sigm(gf) * cp[k] + sigm(gi) * tanhf(gg);
                    const float hn = sigm(go) * tanhf(cn);
                    if (lane == 0) {
                        cb[(size_t)i * HH + u]   = cn;
                        hb_w[(size_t)i * HH + u] = hn;
                    }
                }
            }
            grid_barrier(bar);
        }

        // enc: ctx[i][u] = tanh(W_enc[u] . [hl|hr] + b_enc[u]); per-node parity
        if (B > 0) {
            const int lhalf = lane >> 5;          // 0 -> hl, 1 -> hr
            const int col   = (lane * 16) & 511;
            for (int slot = egrp; slot < B; slot += 4) {
                const int e   = curList[slot];
                const int i   = e & 0xFFF;
                const int len = (e >> (12 + 4 * lhalf)) & 0xF;
                const float* hv = hbuf + (size_t)((((len - 1) & 1)) * 2 + lhalf) * NNHH
                                + (size_t)i * HH + col;
                float acc = 0.f;
#pragma unroll
                for (int j = 0; j < 4; ++j) {
                    const float4 t = *(const float4*)(hv + j * 4);
                    acc += wenc[j * 4 + 0] * t.x + wenc[j * 4 + 1] * t.y +
                           wenc[j * 4 + 2] * t.z + wenc[j * 4 + 3] * t.w;
                }
#pragma unroll
                for (int m = 1; m < 64; m <<= 1) acc += __shfl_xor(acc, m, 64);
                if (lane == 0) ctx[(size_t)i * DD + u] = tanhf(acc + bencv);
            }
        }
        grid_barrier(bar);
        Bprev = B;
        ++r;
    }
}

extern "C" void kernel_launch(void* const* d_in, const int* in_sizes, int n_in,
                              void* d_out, int out_size, void* d_ws, size_t ws_size,
                              hipStream_t stream) {
    hipMemsetAsync(d_ws, 0, WS_ZERO_BYTES, stream);
    tree_lstm_kernel<<<dim3(NB), dim3(TPB), 0, stream>>>(
        (const float*)d_in[0],
        (const float*)d_in[1], (const float*)d_in[2],
        (const float*)d_in[3], (const float*)d_in[4],
        (const float*)d_in[5], (const float*)d_in[6],
        (const float*)d_in[7], (const float*)d_in[8],
        (const float*)d_in[9], (const float*)d_in[10],
        (const int*)d_in[11], (const int*)d_in[12],
        (float*)d_out, (char*)d_ws);
}